// Round 7
// baseline (442.613 us; speedup 1.0000x reference)
//
#include <hip/hip_runtime.h>

// GR4J daily hydrological model, round 7: transcendental-free serial chains.
// T=4015 steps, WARMUP=365, B=2048 basins. 2-wave decoupled pipeline (R6).
//
// R6 post-mortem: barrier removal was ~neutral (343->323 us). Revised model:
// wave1's r-chain = ~36 cyc FMA + 3 chained trans ops; fitting measured 193
// cyc/step gives trans dependent latency ~50 cyc. R7 removes ALL trans from
// both chains:
//  - srx = sqrt(rx) via 0x5f3759df rsqrt bit-trick + 2 Newtons, srx = rx*t
//    (rel ~5e-6; rx clamped >= 1e-12 so t^2 can't overflow at rx=0).
//  - y = (1+z)^(-1/4) via quadratic seed (x in [1,3.5], err <= 2e-2) + 2
//    Newtons y <- y*(1.25 - 0.25*x*y^4) (rel ~3e-6; qr err <= ~6e-4 worst).
//  - s-chain rcp(dp*de): dp*de = 1+eps, eps <= 0.021 -> 1 - eps + eps^2
//    (rel err <= 8.1e-6).
// Rebalance: UH conv moved to wave0 (wave1 gained Newton VALU work);
// wave0->wave1 handoff is float2 (q9,q1) via ds_write_b64. Conv-history
// reset at t=365 now lives in wave0's fully-unrolled k=6 batch.
//
// Expected: wave1-bound ~125-140 cyc/step -> ~210-240 us.

#define T_TOTAL 4015
#define NWARM   365
#define NB      2048
#define BSTEP   55
#define NBATCH  73          // 73 * 55 = 4015

__global__ __launch_bounds__(128, 1)
void gr4j_kernel(const float2* __restrict__ pe_in,   // [T_TOTAL*NB] (p,e)
                 const float*  __restrict__ params,  // [NB,4]
                 float*        __restrict__ out)     // [(T_TOTAL-NWARM)*NB]
{
    const int lane = threadIdx.x & 63;
    const int wid  = threadIdx.x >> 6;
    const int b    = blockIdx.x * 64 + lane;

    __shared__ float2 prbuf[2][BSTEP * 64];          // 56.3 KB double buffer
    __shared__ int produced;
    __shared__ int consumed;
    if (threadIdx.x == 0) { produced = 0; consumed = 0; }
    __syncthreads();   // only barrier: flag init

    const float x1 = 100.0f + params[b * 4 + 0] * 1100.0f;
    const float x2 = -5.0f  + params[b * 4 + 1] * 8.0f;
    const float x3 = 20.0f  + params[b * 4 + 2] * 280.0f;
    const float x4 = 1.1f   + params[b * 4 + 3] * 1.8f;
    const float invx1 = __builtin_amdgcn_rcpf(x1);
    const float invx3 = __builtin_amdgcn_rcpf(x3);
    const float c49   = (4.0f / 9.0f) * invx1;
    const float c49_2 = c49 * c49;
    const float c4s   = c49_2 * c49_2;               // ((4/9)/x1)^4
    const float i3_2  = invx3 * invx3;
    const float c4r   = i3_2 * i3_2;                 // (1/x3)^4

    if (wid == 0) {
        // ========== producer: s-chain + UH conv -> (q9,q1) ==========
        float u10, u11, u12, u20, u21, u22, u23, u24, u25;
        {
            float sh[3];
            #pragma unroll
            for (int j = 1; j <= 3; ++j)
                sh[j - 1] = powf(fminf((float)j / x4, 1.0f), 2.5f);
            u10 = sh[0]; u11 = sh[1] - sh[0]; u12 = sh[2] - sh[1];
            float s2h[6];
            #pragma unroll
            for (int j = 1; j <= 6; ++j) {
                float rr = (float)j / x4;
                s2h[j - 1] = ((float)j <= x4) ? 0.5f * powf(rr, 2.5f)
                           : 1.0f - 0.5f * powf(fmaxf(2.0f - rr, 0.0f), 2.5f);
            }
            u20 = s2h[0];          u21 = s2h[1] - s2h[0]; u22 = s2h[2] - s2h[1];
            u23 = s2h[3] - s2h[2]; u24 = s2h[4] - s2h[3]; u25 = s2h[5] - s2h[4];
        }

        float s = 0.5f * x1;
        float ph0 = 0.f, ph1 = 0.f, ph2 = 0.f, ph3 = 0.f, ph4 = 0.f;

        auto prod_step = [&](float2 pe) -> float2 {
            const float diff = pe.x - pe.y;
            const float pn = fmaxf(diff, 0.0f);
            const float en = fmaxf(-diff, 0.0f);
            const float ap = pn * invx1;             // ~= tanh(pn/x1)
            const float ae = en * invx1;             // ~= tanh(en/x1)
            const float sx = s * invx1;
            const float dp = fmaf(sx, ap, 1.0f);
            const float de = fmaf(1.0f - sx, ae, 1.0f);
            const float n1 = fmaf(-sx, sx, 1.0f);
            const float nump = pn * n1;              // x1*(1-sx^2)*(pn/x1)
            const float nume = (sx * en) * (2.0f - sx);
            // 1/(dp*de) = 1/(1+eps), eps <= 0.021: series 1 - eps + eps^2
            const float dpde = dp * de;
            const float eps  = dpde - 1.0f;
            const float rpe  = fmaf(eps, eps - 1.0f, 1.0f);
            const float a_ = nump * de;
            const float b_ = nume * dp;
            const float s2 = fmaf(a_ - b_, rpe, s);  // s - es + ps
            const float ps = a_ * rpe;
            const float s22 = s2 * s2;
            const float s24 = s22 * s22;
            const float z = c4s * s24;               // <= 0.039
            float w = fmaf(z, 15.0f / 128.0f, -5.0f / 32.0f);
            w = fmaf(z, w, 0.25f);
            const float perc = (s2 * z) * w;         // s2*(1-(1+z)^-.25)
            s = s2 - perc;
            const float pr = perc + (pn - ps);
            const float q9 = fmaf(u10, pr, fmaf(u11, ph0, u12 * ph1));
            const float q1 = fmaf(u20, pr, fmaf(u21, ph0, fmaf(u22, ph1,
                             fmaf(u23, ph2, fmaf(u24, ph3, u25 * ph4)))));
            ph4 = ph3; ph3 = ph2; ph2 = ph1; ph1 = ph0; ph0 = pr;
            return make_float2(q9, q1);
        };

        const float2* gptr = pe_in + b;
        float2 rot[11];
        #pragma unroll
        for (int i = 0; i < 11; ++i) rot[i] = gptr[(size_t)i * NB];

        for (int k = 0; k < NBATCH; ++k) {
            if (k >= 2) {
                while (__hip_atomic_load(&consumed, __ATOMIC_ACQUIRE,
                                         __HIP_MEMORY_SCOPE_WORKGROUP) < k - 1) {}
            }
            float2* dst = &prbuf[k & 1][0] + lane;
            const int tb = k * BSTEP;
            if (k != 6) {
                const int grf = (k < NBATCH - 1) ? 5 : 4;   // groups w/ refill
                for (int g = 0; g < 5; ++g) {
                    float2* d2 = dst + g * (11 * 64);
                    if (g < grf) {
                        const float2* gp = gptr + (size_t)(tb + g * 11 + 11) * NB;
                        #pragma unroll
                        for (int i = 0; i < 11; ++i) {
                            const float2 pe = rot[i];
                            rot[i] = gp[(size_t)i * NB];    // load t+11
                            d2[i * 64] = prod_step(pe);
                        }
                    } else {                                // final-batch drain
                        #pragma unroll
                        for (int i = 0; i < 11; ++i)
                            d2[i * 64] = prod_step(rot[i]);
                    }
                }
            } else {
                // k=6: t=330..384, fully unrolled; conv history resets
                // before t=365 (j==35): reference restarts _gr4j_core at
                // WARMUP (s carries over, conv history does not).
                const float2* gp = gptr + (size_t)(tb + 11) * NB;
                #pragma unroll
                for (int j = 0; j < 55; ++j) {
                    const int i = j % 11;                   // compile-time
                    if (j == 35) { ph0 = ph1 = ph2 = ph3 = ph4 = 0.0f; }
                    const float2 pe = rot[i];
                    rot[i] = gp[(size_t)j * NB];            // load t+11
                    dst[j * 64] = prod_step(pe);
                }
            }
            __hip_atomic_store(&produced, k + 1, __ATOMIC_RELEASE,
                               __HIP_MEMORY_SCOPE_WORKGROUP);
        }
    } else {
        // ============== consumer: r-chain + output store ==============
        float r = 0.5f * x3;

        auto route_q = [&](float2 qq) -> float {
            const float q9 = qq.x, q1 = qq.y;
            float rx = fmaxf(r * invx3, 1e-12f);
            // srx = sqrt(rx) = rx * rsqrt(rx), bit-trick + 2 Newtons
            const float hx = 0.5f * rx;
            unsigned ib = __float_as_uint(rx);
            ib = 0x5f3759dfu - (ib >> 1);
            float t = __uint_as_float(ib);
            t = t * fmaf(-hx * t, t, 1.5f);
            t = t * fmaf(-hx * t, t, 1.5f);
            const float srx = rx * t;
            const float rx3 = (rx * rx) * rx;
            const float gex = (x2 * rx3) * srx;      // x2*(r/x3)^3.5
            const float r2 = fmaxf(0.0f, (r + q9) + gex);
            const float r22 = r2 * r2;
            const float r24 = r22 * r22;
            const float xx = fmaf(c4r, r24, 1.0f);   // 1+v^4, in [1, ~3.5]
            // y = xx^(-1/4): quadratic seed + 2 Newtons
            const float qx = 0.25f * xx;
            float y = fmaf(xx, fmaf(xx, 0.034855f, -0.26206f), 1.22721f);
            {
                const float y2 = y * y;
                const float y4 = y2 * y2;
                y = y * fmaf(-qx, y4, 1.25f);
            }
            {
                const float y2 = y * y;
                const float y4 = y2 * y2;
                y = y * fmaf(-qx, y4, 1.25f);
            }
            const float rn = r2 * y;
            const float qr = r2 - rn;
            r = rn;
            return qr + fmaxf(0.0f, q1 + gex);
        };

        for (int k = 0; k < NBATCH; ++k) {
            while (__hip_atomic_load(&produced, __ATOMIC_ACQUIRE,
                                     __HIP_MEMORY_SCOPE_WORKGROUP) < k + 1) {}
            const float2* src = &prbuf[k & 1][0] + lane;
            if (k != 6) {
                // k<6: dump rows [t] (overwritten later by real rows, same
                // wave => program-ordered). k>=7: real rows [t-365].
                float* ob = (k < 6)
                    ? out + (size_t)(k * BSTEP) * NB + b
                    : out + (size_t)(k * BSTEP - NWARM) * NB + b;
                float2 prr[11];
                #pragma unroll
                for (int i = 0; i < 11; ++i) prr[i] = src[i * 64];
                for (int g = 0; g < 5; ++g) {
                    const float2* sp = src + (g + 1) * (11 * 64);
                    float* ob2 = ob + (size_t)(g * 11) * NB;
                    if (g < 4) {
                        #pragma unroll
                        for (int i = 0; i < 11; ++i) {
                            const float2 qq = prr[i];
                            prr[i] = sp[i * 64];            // prefetch 11 ahead
                            ob2[(size_t)i * NB] = route_q(qq);
                        }
                    } else {
                        #pragma unroll
                        for (int i = 0; i < 11; ++i)
                            ob2[(size_t)i * NB] = route_q(prr[i]);
                    }
                }
            } else {
                // k=6: t=330..384; store base switches dump->real at t=365.
                float* dumpb = out + (size_t)330 * NB + b;  // rows 330..364
                float* realb = out + b;                     // rows 0..19
                float2 prr[11];
                #pragma unroll
                for (int i = 0; i < 11; ++i) prr[i] = src[i * 64];
                #pragma unroll
                for (int g = 0; g < 5; ++g) {
                    #pragma unroll
                    for (int i = 0; i < 11; ++i) {
                        const int j = g * 11 + i;
                        const float2 qq = prr[i];
                        if (g < 4) prr[i] = src[(j + 11) * 64];
                        const float q = route_q(qq);
                        if (j < 35) dumpb[(size_t)j * NB] = q;
                        else        realb[(size_t)(j - 35) * NB] = q;
                    }
                }
            }
            __hip_atomic_store(&consumed, k + 1, __ATOMIC_RELEASE,
                               __HIP_MEMORY_SCOPE_WORKGROUP);
        }
    }
}

extern "C" void kernel_launch(void* const* d_in, const int* in_sizes, int n_in,
                              void* d_out, int out_size, void* d_ws, size_t ws_size,
                              hipStream_t stream) {
    const float2* pe_in  = (const float2*)d_in[0];   // p_and_e [4015,2048,2]
    const float*  params = (const float*)d_in[1];    // parameters [2048,4]
    float* out = (float*)d_out;                      // [3650,2048,1]
    (void)in_sizes; (void)n_in; (void)out_size; (void)d_ws; (void)ws_size;

    gr4j_kernel<<<dim3(NB / 64), dim3(128), 0, stream>>>(pe_in, params, out);
}